// Round 1
// baseline (2554.900 us; speedup 1.0000x reference)
//
#include <hip/hip_runtime.h>
#include <hip/hip_bf16.h>

// Problem constants
#define B_ 64
#define S_ 512
#define E_ 1024
#define P_ 200
#define K_ 10
#define C_ 3

// GEMM tiling
#define BM 64   // s rows per tile
#define BN 80   // pk cols per tile (8 protos * 10)
#define BK 16   // e per step

// distances[b,p,s,k] = sqrt(max(x2[b,s] + y2[p,k] - 2*xy, 0))
__global__ __launch_bounds__(256) void dist_gemm(const float* __restrict__ emb,
                                                 const float* __restrict__ proto,
                                                 float* __restrict__ dist) {
    const int nt = blockIdx.x;   // 0..24
    const int st = blockIdx.y;   // 0..7
    const int b  = blockIdx.z;   // 0..63

    __shared__ float As[BK][BM + 1];   // [e][s]
    __shared__ float Bs[BK][BN + 1];   // [e][pk]
    __shared__ float x2s[BM];
    __shared__ float y2s[BN];

    const int tid = threadIdx.x;
    const int tx = tid & 15;        // 0..15 -> 5 cols each
    const int ty = tid >> 4;        // 0..15 -> 4 rows each

    if (tid < BM) x2s[tid] = 0.f;
    if (tid < BN) y2s[tid] = 0.f;

    float acc[4][5];
#pragma unroll
    for (int i = 0; i < 4; ++i)
#pragma unroll
        for (int j = 0; j < 5; ++j) acc[i][j] = 0.f;

    const float* Ab = emb + ((size_t)b * S_ + (size_t)st * BM) * E_;
    const float* Bb = proto + (size_t)nt * BN * E_;

    for (int e0 = 0; e0 < E_; e0 += BK) {
        __syncthreads();   // protect As/Bs/x2s from previous iteration's readers
        // Load A tile: 64 rows x 16 cols (1024 elems, 4 per thread)
#pragma unroll
        for (int i = 0; i < 4; ++i) {
            int r = (tid >> 4) + 16 * i;
            int c = tid & 15;
            As[c][r] = Ab[(size_t)r * E_ + e0 + c];
        }
        // Load B tile: 80 rows x 16 cols (1280 elems, 5 per thread)
#pragma unroll
        for (int i = 0; i < 5; ++i) {
            int idx = tid + 256 * i;
            int r = idx >> 4;
            int c = idx & 15;
            Bs[c][r] = Bb[(size_t)r * E_ + e0 + c];
        }
        __syncthreads();
        // Fold x2 / y2 accumulation into the K loop (subset of threads)
        if (tid < BM) {
            float s = 0.f;
#pragma unroll
            for (int kk = 0; kk < BK; ++kk) { float v = As[kk][tid]; s += v * v; }
            x2s[tid] += s;
        } else if (tid >= 128 && tid < 128 + BN) {
            int c = tid - 128;
            float s = 0.f;
#pragma unroll
            for (int kk = 0; kk < BK; ++kk) { float v = Bs[kk][c]; s += v * v; }
            y2s[c] += s;
        }
        // FMA micro-tile
#pragma unroll
        for (int kk = 0; kk < BK; ++kk) {
            float a[4], bv[5];
#pragma unroll
            for (int i = 0; i < 4; ++i) a[i] = As[kk][ty * 4 + i];
#pragma unroll
            for (int j = 0; j < 5; ++j) bv[j] = Bs[kk][tx * 5 + j];
#pragma unroll
            for (int i = 0; i < 4; ++i)
#pragma unroll
                for (int j = 0; j < 5; ++j) acc[i][j] += a[i] * bv[j];
        }
    }
    __syncthreads();   // x2s/y2s complete before epilogue

#pragma unroll
    for (int i = 0; i < 4; ++i) {
        int s = st * BM + ty * 4 + i;
        float x2 = x2s[ty * 4 + i];
#pragma unroll
        for (int j = 0; j < 5; ++j) {
            int n = nt * BN + tx * 5 + j;
            int p = n / K_;
            int k = n % K_;
            float d2 = x2 + y2s[tx * 5 + j] - 2.f * acc[i][j];
            dist[(((size_t)b * P_ + p) * S_ + s) * K_ + k] = sqrtf(fmaxf(d2, 0.f));
        }
    }
}

// One block per (b,p): min over s (512) for each k, then mean over k
__global__ __launch_bounds__(256) void min_mean(const float* __restrict__ dist,
                                                float* __restrict__ pd) {
    const int p = blockIdx.x;
    const int b = blockIdx.y;
    const float* dp = dist + ((size_t)b * P_ + p) * (size_t)(S_ * K_);
    const int tid = threadIdx.x;

    float mn[K_];
#pragma unroll
    for (int k = 0; k < K_; ++k) mn[k] = 3.4e38f;

    for (int s = tid; s < S_; s += 256) {
        const float* row = dp + (size_t)s * K_;
#pragma unroll
        for (int k = 0; k < K_; ++k) mn[k] = fminf(mn[k], row[k]);
    }

    __shared__ float red[256];
    __shared__ float ksum;
    if (tid == 0) ksum = 0.f;
    for (int k = 0; k < K_; ++k) {
        __syncthreads();
        red[tid] = mn[k];
        __syncthreads();
        for (int off = 128; off > 0; off >>= 1) {
            if (tid < off) red[tid] = fminf(red[tid], red[tid + off]);
            __syncthreads();
        }
        if (tid == 0) ksum += red[0];
    }
    __syncthreads();
    if (tid == 0) pd[b * P_ + p] = ksum * (1.0f / K_);
}

// class_out[b,c] = sum_p pd[b,p] * fc[c,p]
__global__ void fc_kernel(const float* __restrict__ pd, const float* __restrict__ fc,
                          float* __restrict__ cls) {
    int tid = threadIdx.x;
    if (tid < B_ * C_) {
        int b = tid / C_;
        int c = tid % C_;
        float s = 0.f;
        for (int p = 0; p < P_; ++p) s += pd[b * P_ + p] * fc[c * P_ + p];
        cls[b * C_ + c] = s;
    }
}

extern "C" void kernel_launch(void* const* d_in, const int* in_sizes, int n_in,
                              void* d_out, int out_size, void* d_ws, size_t ws_size,
                              hipStream_t stream) {
    const float* emb   = (const float*)d_in[0];   // [64,512,1024]
    const float* proto = (const float*)d_in[1];   // [200,10,1024]
    const float* fc    = (const float*)d_in[2];   // [3,200]
    float* out = (float*)d_out;

    float* pd   = out;                              // [64,200]
    float* dist = out + (size_t)B_ * P_;            // [64,200,512,10]
    float* cls  = out + (size_t)B_ * P_ + (size_t)B_ * P_ * S_ * K_;  // [64,3]

    dim3 ggrid(P_ * K_ / BN, S_ / BM, B_);          // (25, 8, 64)
    dist_gemm<<<ggrid, 256, 0, stream>>>(emb, proto, dist);
    min_mean<<<dim3(P_, B_), 256, 0, stream>>>(dist, pd);
    fc_kernel<<<1, 256, 0, stream>>>(pd, fc, cls);
}

// Round 2
// 1338.471 us; speedup vs baseline: 1.9088x; 1.9088x over previous
//
#include <hip/hip_runtime.h>
#include <hip/hip_bf16.h>

#define B_ 64
#define S_ 512
#define E_ 1024
#define P_ 200
#define K_ 10
#define C_ 3

#define BM 128
#define BN 80
#define BKS 64   // K elements per LDS stage

typedef __attribute__((ext_vector_type(8))) short short8;
typedef __attribute__((ext_vector_type(4))) float f32x4;

__device__ __forceinline__ float bf2f(short u) {
    unsigned int x = ((unsigned int)(unsigned short)u) << 16;
    return __uint_as_float(x);
}

__device__ __forceinline__ unsigned short f2bf(float f) {
    __hip_bfloat16 h = __float2bfloat16(f);
    unsigned short u;
    __builtin_memcpy(&u, &h, 2);
    return u;
}

// Swizzled LDS byte offset: row-major [row][k] bf16, row stride 64 elem = 128 B,
// XOR row&7 into the 16B-slot bits -> breaks the stride-128B bank conflict (T2/G4).
__device__ __forceinline__ int swz(int row, int kbyte) {
    return (row * (BKS * 2) + kbyte) ^ ((row & 7) << 4);
}

__global__ __launch_bounds__(256) void dist_mfma(const float* __restrict__ emb,
                                                 const float* __restrict__ proto,
                                                 float* __restrict__ dist) {
    __shared__ short As[BM * BKS];   // 16 KB
    __shared__ short Bs[BN * BKS];   // 10 KB
    __shared__ float x2s[BM];
    __shared__ float y2s[BN];

    const int tid  = threadIdx.x;
    const int lane = tid & 63;
    const int wv   = tid >> 6;
    const int nt = blockIdx.x;   // 0..24
    const int mt = blockIdx.y;   // 0..255

    const float* Ab = emb + (size_t)mt * BM * E_;
    const float* Bb = proto + (size_t)nt * BN * E_;

    f32x4 acc[2][5];
#pragma unroll
    for (int i = 0; i < 2; ++i)
#pragma unroll
        for (int j = 0; j < 5; ++j) acc[i][j] = (f32x4){0.f, 0.f, 0.f, 0.f};

    float x2a = 0.f, y2a = 0.f;
    const int l15 = lane & 15;
    const int lh  = lane >> 4;

    for (int e0 = 0; e0 < E_; e0 += BKS) {
        __syncthreads();   // previous iteration's readers done
        // Stage A: 128 rows x 64 cols f32 -> bf16. 2048 float4, 8 per thread, coalesced.
#pragma unroll
        for (int i = 0; i < 8; ++i) {
            int idx = i * 256 + tid;
            int r = idx >> 4, c4 = idx & 15;
            float4 v = *(const float4*)(Ab + (size_t)r * E_ + e0 + c4 * 4);
            ushort4 h = { f2bf(v.x), f2bf(v.y), f2bf(v.z), f2bf(v.w) };
            *(ushort4*)((char*)As + swz(r, c4 * 8)) = h;
        }
        // Stage B: 80 rows x 64 cols. 1280 float4, 5 per thread.
#pragma unroll
        for (int i = 0; i < 5; ++i) {
            int idx = i * 256 + tid;
            int r = idx >> 4, c4 = idx & 15;
            float4 v = *(const float4*)(Bb + (size_t)r * E_ + e0 + c4 * 4);
            ushort4 h = { f2bf(v.x), f2bf(v.y), f2bf(v.z), f2bf(v.w) };
            *(ushort4*)((char*)Bs + swz(r, c4 * 8)) = h;
        }
        __syncthreads();

        // x2/y2 partial sums from the SAME bf16 values the MFMA consumes
        // (error in d2 = x2+y2-2xy partially cancels: d ~= ||a_hat - b_hat||)
        if (tid < BM) {
#pragma unroll
            for (int kb = 0; kb < 8; ++kb) {
                short8 a = *(const short8*)((const char*)As + swz(tid, kb * 16));
#pragma unroll
                for (int j = 0; j < 8; ++j) { float f = bf2f(a[j]); x2a += f * f; }
            }
        } else if (tid < BM + BN) {
            int c = tid - BM;
#pragma unroll
            for (int kb = 0; kb < 8; ++kb) {
                short8 bv = *(const short8*)((const char*)Bs + swz(c, kb * 16));
#pragma unroll
                for (int j = 0; j < 8; ++j) { float f = bf2f(bv[j]); y2a += f * f; }
            }
        }

        // MFMA: per wave 2 m-frags x 5 n-frags, 2 K-steps of 32
#pragma unroll
        for (int kk = 0; kk < 2; ++kk) {
            const int kbyte = kk * 64 + lh * 16;   // (kk*32 + lh*8) bf16 -> bytes
            short8 af[2];
#pragma unroll
            for (int mf = 0; mf < 2; ++mf) {
                int row = wv * 32 + mf * 16 + l15;
                af[mf] = *(const short8*)((const char*)As + swz(row, kbyte));
            }
            short8 bfr[5];
#pragma unroll
            for (int nf = 0; nf < 5; ++nf) {
                int col = nf * 16 + l15;
                bfr[nf] = *(const short8*)((const char*)Bs + swz(col, kbyte));
            }
#pragma unroll
            for (int mf = 0; mf < 2; ++mf)
#pragma unroll
                for (int nf = 0; nf < 5; ++nf)
                    acc[mf][nf] = __builtin_amdgcn_mfma_f32_16x16x32_bf16(
                        af[mf], bfr[nf], acc[mf][nf], 0, 0, 0);
        }
    }

    if (tid < BM) x2s[tid] = x2a;
    else if (tid < BM + BN) y2s[tid - BM] = y2a;
    __syncthreads();

    // Epilogue: d = sqrt(max(x2 + y2 - 2*xy, 0)), write [b,p,s,k]
    // C/D layout: col = lane&15, row = (lane>>4)*4 + reg
#pragma unroll
    for (int mf = 0; mf < 2; ++mf) {
#pragma unroll
        for (int nf = 0; nf < 5; ++nf) {
#pragma unroll
            for (int rg = 0; rg < 4; ++rg) {
                int ml = wv * 32 + mf * 16 + lh * 4 + rg;
                int nl = nf * 16 + l15;
                int m = mt * BM + ml;
                int n = nt * BN + nl;
                int b = m >> 9;
                int s = m & (S_ - 1);
                int p = n / K_;
                int k = n - p * K_;
                float d2 = x2s[ml] + y2s[nl] - 2.f * acc[mf][nf][rg];
                dist[(((size_t)b * P_ + p) * S_ + s) * K_ + k] = sqrtf(fmaxf(d2, 0.f));
            }
        }
    }
}

// One block per (b,p): min over s for each k, then mean over k.
// Thread t handles s-pair (2t, 2t+1) = 20 contiguous floats = 5 aligned float4.
__global__ __launch_bounds__(256) void min_mean(const float* __restrict__ dist,
                                                float* __restrict__ pd) {
    const int p = blockIdx.x;
    const int b = blockIdx.y;
    const float* dp = dist + ((size_t)b * P_ + p) * (size_t)(S_ * K_);
    const int tid = threadIdx.x;

    const float4* base = (const float4*)(dp + (size_t)tid * 20);
    float4 q0 = base[0], q1 = base[1], q2 = base[2], q3 = base[3], q4 = base[4];

    float mn[K_];
    mn[0] = fminf(q0.x, q2.z); mn[1] = fminf(q0.y, q2.w);
    mn[2] = fminf(q0.z, q3.x); mn[3] = fminf(q0.w, q3.y);
    mn[4] = fminf(q1.x, q3.z); mn[5] = fminf(q1.y, q3.w);
    mn[6] = fminf(q1.z, q4.x); mn[7] = fminf(q1.w, q4.y);
    mn[8] = fminf(q2.x, q4.z); mn[9] = fminf(q2.y, q4.w);

    // full-wave butterfly reduce for each k
#pragma unroll
    for (int k = 0; k < K_; ++k) {
#pragma unroll
        for (int off = 32; off > 0; off >>= 1)
            mn[k] = fminf(mn[k], __shfl_xor(mn[k], off));
    }

    __shared__ float red[4][K_];
    if ((tid & 63) == 0) {
#pragma unroll
        for (int k = 0; k < K_; ++k) red[tid >> 6][k] = mn[k];
    }
    __syncthreads();
    if (tid == 0) {
        float sum = 0.f;
#pragma unroll
        for (int k = 0; k < K_; ++k)
            sum += fminf(fminf(red[0][k], red[1][k]), fminf(red[2][k], red[3][k]));
        pd[b * P_ + p] = sum * (1.0f / K_);
    }
}

__global__ void fc_kernel(const float* __restrict__ pd, const float* __restrict__ fc,
                          float* __restrict__ cls) {
    int tid = threadIdx.x;
    if (tid < B_ * C_) {
        int b = tid / C_;
        int c = tid % C_;
        float s = 0.f;
        for (int p = 0; p < P_; ++p) s += pd[b * P_ + p] * fc[c * P_ + p];
        cls[b * C_ + c] = s;
    }
}

extern "C" void kernel_launch(void* const* d_in, const int* in_sizes, int n_in,
                              void* d_out, int out_size, void* d_ws, size_t ws_size,
                              hipStream_t stream) {
    const float* emb   = (const float*)d_in[0];   // [64,512,1024]
    const float* proto = (const float*)d_in[1];   // [200,10,1024]
    const float* fc    = (const float*)d_in[2];   // [3,200]
    float* out = (float*)d_out;

    float* pd   = out;                                                // [64,200]
    float* dist = out + (size_t)B_ * P_;                              // [64,200,512,10]
    float* cls  = out + (size_t)B_ * P_ + (size_t)B_ * P_ * S_ * K_;  // [64,3]

    // x fastest: 25 consecutive blocks share one A-tile -> L2 hits on re-read
    dim3 ggrid(P_ * K_ / BN, (B_ * S_) / BM, 1);   // (25, 256)
    dist_mfma<<<ggrid, 256, 0, stream>>>(emb, proto, dist);
    min_mean<<<dim3(P_, B_), 256, 0, stream>>>(dist, pd);
    fc_kernel<<<1, 256, 0, stream>>>(pd, fc, cls);
}

// Round 3
// 466.253 us; speedup vs baseline: 5.4796x; 2.8707x over previous
//
#include <hip/hip_runtime.h>
#include <hip/hip_bf16.h>

#define B_ 64
#define S_ 512
#define E_ 1024
#define P_ 200
#define K_ 10
#define C_ 3

#define BM 128
#define BN 80
#define BKS 64   // K elements per LDS stage
#define NSTAGE (E_ / BKS)   // 16

typedef __attribute__((ext_vector_type(8))) short short8;
typedef __attribute__((ext_vector_type(4))) float f32x4;

__device__ __forceinline__ unsigned short f2bf(float f) {
    __hip_bfloat16 h = __float2bfloat16(f);
    unsigned short u;
    __builtin_memcpy(&u, &h, 2);
    return u;
}

// Swizzled LDS byte offset: row-major [row][k] bf16, row stride 128 B.
// XOR row&7 into the 16B-slot bits (T2/G4: breaks stride-128B bank conflict).
__device__ __forceinline__ int swz(int row, int kbyte) {
    return (row * (BKS * 2) + kbyte) ^ ((row & 7) << 4);
}

__global__ __launch_bounds__(256) void dist_mfma(const float* __restrict__ emb,
                                                 const float* __restrict__ proto,
                                                 float* __restrict__ dist) {
    __shared__ short As[BM * BKS];   // 16 KB
    __shared__ short Bs[BN * BKS];   // 10 KB
    __shared__ float x2s[BM];
    __shared__ float y2s[BN];

    const int tid  = threadIdx.x;
    const int lane = tid & 63;
    const int wv   = tid >> 6;
    const int l15  = lane & 15;
    const int lh   = lane >> 4;

    // XCD-aware swizzle: 6400 blocks, 6400%8==0 -> bijective simple form.
    // Each XCD gets 800 consecutive work-units = 32 m-tiles x all 25 n-tiles.
    const int id = blockIdx.x;
    const int sw = (id & 7) * (6400 / 8) + (id >> 3);
    const int nt = sw % 25;
    const int mt = sw / 25;

    const float* Ab = emb + (size_t)mt * BM * E_ + (size_t)(tid >> 4) * E_ + (tid & 15) * 4;
    const float* Bb = proto + (size_t)nt * BN * E_ + (size_t)(tid >> 4) * E_ + (tid & 15) * 4;

    f32x4 acc[2][5];
#pragma unroll
    for (int i = 0; i < 2; ++i)
#pragma unroll
        for (int j = 0; j < 5; ++j) acc[i][j] = (f32x4){0.f, 0.f, 0.f, 0.f};

    float x2p[8], y2p[5];
#pragma unroll
    for (int i = 0; i < 8; ++i) x2p[i] = 0.f;
#pragma unroll
    for (int i = 0; i < 5; ++i) y2p[i] = 0.f;

    float4 pa[8], pb[5];
    // prologue: issue loads for stage 0
#pragma unroll
    for (int i = 0; i < 8; ++i) pa[i] = *(const float4*)(Ab + (size_t)i * 16 * E_);
#pragma unroll
    for (int i = 0; i < 5; ++i) pb[i] = *(const float4*)(Bb + (size_t)i * 16 * E_);

    for (int t = 0; t < NSTAGE; ++t) {
        // convert prefetched regs -> bf16, accumulate |.|^2 partials (f32-exact)
        ushort4 ca[8];
#pragma unroll
        for (int i = 0; i < 8; ++i) {
            float4 v = pa[i];
            x2p[i] += v.x * v.x + v.y * v.y + v.z * v.z + v.w * v.w;
            ca[i] = (ushort4){ f2bf(v.x), f2bf(v.y), f2bf(v.z), f2bf(v.w) };
        }
        ushort4 cb[5];
#pragma unroll
        for (int i = 0; i < 5; ++i) {
            float4 v = pb[i];
            y2p[i] += v.x * v.x + v.y * v.y + v.z * v.z + v.w * v.w;
            cb[i] = (ushort4){ f2bf(v.x), f2bf(v.y), f2bf(v.z), f2bf(v.w) };
        }

        __syncthreads();   // all waves done reading LDS (previous stage)
#pragma unroll
        for (int i = 0; i < 8; ++i) {
            int idx = i * 256 + tid;
            *(ushort4*)((char*)As + swz(idx >> 4, (idx & 15) * 8)) = ca[i];
        }
#pragma unroll
        for (int i = 0; i < 5; ++i) {
            int idx = i * 256 + tid;
            *(ushort4*)((char*)Bs + swz(idx >> 4, (idx & 15) * 8)) = cb[i];
        }
        __syncthreads();   // stage visible

        // issue next stage's loads NOW -> latency hides under MFMA + next cvt
        if (t + 1 < NSTAGE) {
            const float* An = Ab + (size_t)(t + 1) * BKS;
            const float* Bn = Bb + (size_t)(t + 1) * BKS;
#pragma unroll
            for (int i = 0; i < 8; ++i) pa[i] = *(const float4*)(An + (size_t)i * 16 * E_);
#pragma unroll
            for (int i = 0; i < 5; ++i) pb[i] = *(const float4*)(Bn + (size_t)i * 16 * E_);
        }

        // MFMA: per wave 2 m-frags x 5 n-frags, 2 K-steps of 32
#pragma unroll
        for (int kk = 0; kk < 2; ++kk) {
            const int kbyte = kk * 64 + lh * 16;
            short8 af[2];
#pragma unroll
            for (int mf = 0; mf < 2; ++mf) {
                int row = wv * 32 + mf * 16 + l15;
                af[mf] = *(const short8*)((const char*)As + swz(row, kbyte));
            }
            short8 bfr[5];
#pragma unroll
            for (int nf = 0; nf < 5; ++nf) {
                int col = nf * 16 + l15;
                bfr[nf] = *(const short8*)((const char*)Bs + swz(col, kbyte));
            }
#pragma unroll
            for (int mf = 0; mf < 2; ++mf)
#pragma unroll
                for (int nf = 0; nf < 5; ++nf)
                    acc[mf][nf] = __builtin_amdgcn_mfma_f32_16x16x32_bf16(
                        af[mf], bfr[nf], acc[mf][nf], 0, 0, 0);
        }
    }

    // Reduce x2/y2 partials over the 16-lane row groups (rows stable per thread)
#pragma unroll
    for (int i = 0; i < 8; ++i) {
        float v = x2p[i];
        v += __shfl_xor(v, 1); v += __shfl_xor(v, 2);
        v += __shfl_xor(v, 4); v += __shfl_xor(v, 8);
        if (l15 == 0) x2s[16 * i + (tid >> 4)] = v;
    }
#pragma unroll
    for (int i = 0; i < 5; ++i) {
        float v = y2p[i];
        v += __shfl_xor(v, 1); v += __shfl_xor(v, 2);
        v += __shfl_xor(v, 4); v += __shfl_xor(v, 8);
        if (l15 == 0) y2s[16 * i + (tid >> 4)] = v;
    }
    __syncthreads();

    // Epilogue: d = sqrt(max(x2 + y2 - 2*xy, 0)), write [b,p,s,k]
    // C/D layout: col = lane&15, row = (lane>>4)*4 + reg
#pragma unroll
    for (int mf = 0; mf < 2; ++mf) {
#pragma unroll
        for (int nf = 0; nf < 5; ++nf) {
#pragma unroll
            for (int rg = 0; rg < 4; ++rg) {
                int ml = wv * 32 + mf * 16 + lh * 4 + rg;
                int nl = nf * 16 + l15;
                int m = mt * BM + ml;
                int n = nt * BN + nl;
                int b = m >> 9;
                int s = m & (S_ - 1);
                int p = n / K_;
                int k = n - p * K_;
                float d2 = x2s[ml] + y2s[nl] - 2.f * acc[mf][nf][rg];
                dist[(((size_t)b * P_ + p) * S_ + s) * K_ + k] = sqrtf(fmaxf(d2, 0.f));
            }
        }
    }
}

// One block per (b,p): min over s for each k, then mean over k.
// Thread t handles s-pair (2t, 2t+1) = 20 contiguous floats = 5 aligned float4.
__global__ __launch_bounds__(256) void min_mean(const float* __restrict__ dist,
                                                float* __restrict__ pd) {
    const int p = blockIdx.x;
    const int b = blockIdx.y;
    const float* dp = dist + ((size_t)b * P_ + p) * (size_t)(S_ * K_);
    const int tid = threadIdx.x;

    const float4* base = (const float4*)(dp + (size_t)tid * 20);
    float4 q0 = base[0], q1 = base[1], q2 = base[2], q3 = base[3], q4 = base[4];

    float mn[K_];
    mn[0] = fminf(q0.x, q2.z); mn[1] = fminf(q0.y, q2.w);
    mn[2] = fminf(q0.z, q3.x); mn[3] = fminf(q0.w, q3.y);
    mn[4] = fminf(q1.x, q3.z); mn[5] = fminf(q1.y, q3.w);
    mn[6] = fminf(q1.z, q4.x); mn[7] = fminf(q1.w, q4.y);
    mn[8] = fminf(q2.x, q4.z); mn[9] = fminf(q2.y, q4.w);

#pragma unroll
    for (int k = 0; k < K_; ++k) {
#pragma unroll
        for (int off = 32; off > 0; off >>= 1)
            mn[k] = fminf(mn[k], __shfl_xor(mn[k], off));
    }

    __shared__ float red[4][K_];
    if ((tid & 63) == 0) {
#pragma unroll
        for (int k = 0; k < K_; ++k) red[tid >> 6][k] = mn[k];
    }
    __syncthreads();
    if (tid == 0) {
        float sum = 0.f;
#pragma unroll
        for (int k = 0; k < K_; ++k)
            sum += fminf(fminf(red[0][k], red[1][k]), fminf(red[2][k], red[3][k]));
        pd[b * P_ + p] = sum * (1.0f / K_);
    }
}

__global__ void fc_kernel(const float* __restrict__ pd, const float* __restrict__ fc,
                          float* __restrict__ cls) {
    int tid = threadIdx.x;
    if (tid < B_ * C_) {
        int b = tid / C_;
        int c = tid % C_;
        float s = 0.f;
        for (int p = 0; p < P_; ++p) s += pd[b * P_ + p] * fc[c * P_ + p];
        cls[b * C_ + c] = s;
    }
}

extern "C" void kernel_launch(void* const* d_in, const int* in_sizes, int n_in,
                              void* d_out, int out_size, void* d_ws, size_t ws_size,
                              hipStream_t stream) {
    const float* emb   = (const float*)d_in[0];   // [64,512,1024]
    const float* proto = (const float*)d_in[1];   // [200,10,1024]
    const float* fc    = (const float*)d_in[2];   // [3,200]
    float* out = (float*)d_out;

    float* pd   = out;                                                // [64,200]
    float* dist = out + (size_t)B_ * P_;                              // [64,200,512,10]
    float* cls  = out + (size_t)B_ * P_ + (size_t)B_ * P_ * S_ * K_;  // [64,3]

    dist_mfma<<<dim3(25 * 256), 256, 0, stream>>>(emb, proto, dist);
    min_mean<<<dim3(P_, B_), 256, 0, stream>>>(dist, pd);
    fc_kernel<<<1, 256, 0, stream>>>(pd, fc, cls);
}

// Round 4
// 345.794 us; speedup vs baseline: 7.3885x; 1.3484x over previous
//
#include <hip/hip_runtime.h>
#include <hip/hip_bf16.h>

#define B_ 64
#define S_ 512
#define E_ 1024
#define P_ 200
#define K_ 10
#define C_ 3

#define BM 128
#define BN 80
#define BKS 64                 // K elements per LDS stage
#define NSTAGE (E_ / BKS)      // 16
#define NROWS_A (B_ * S_)      // 32768
#define NROWS_B (P_ * K_)      // 2000
#define NROWS_T (NROWS_A + NROWS_B)  // 34768

typedef __attribute__((ext_vector_type(8))) short short8;
typedef __attribute__((ext_vector_type(4))) float f32x4;

__device__ __forceinline__ float bf2f(unsigned short u) {
    unsigned int x = ((unsigned int)u) << 16;
    return __uint_as_float(x);
}
__device__ __forceinline__ unsigned short f2bf(float f) {
    __hip_bfloat16 h = __float2bfloat16(f);
    unsigned short u;
    __builtin_memcpy(&u, &h, 2);
    return u;
}

// Read-side swizzle: row-major [row][64] bf16 (row stride 128 B), logical chunk
// kbyte lives at slot (kbyte>>4)^(row&7). Involution with the staging source swizzle.
__device__ __forceinline__ int swz(int row, int kbyte) {
    return (row * (BKS * 2) + kbyte) ^ ((row & 7) << 4);
}

#define GLDS16(gsrc, ldst)                                                              \
    __builtin_amdgcn_global_load_lds((const __attribute__((address_space(1))) unsigned int*)(gsrc), \
                                     (__attribute__((address_space(3))) unsigned int*)(ldst), 16, 0, 0)

// ---------------------------------------------------------------------------
// Pass 1: f32 -> bf16 for emb (rows 0..32767) and proto (rows 32768..34767),
// plus per-row sum of squares of the bf16-rounded values (consistent with MFMA).
// One wave per row.
__global__ __launch_bounds__(256) void preconvert(const float* __restrict__ emb,
                                                  const float* __restrict__ proto,
                                                  unsigned short* __restrict__ bf,
                                                  float* __restrict__ xy2) {
    const int row  = blockIdx.x * 4 + (threadIdx.x >> 6);
    const int lane = threadIdx.x & 63;
    const float* src = (row < NROWS_A) ? emb + (size_t)row * E_
                                       : proto + (size_t)(row - NROWS_A) * E_;
    unsigned short* dst = bf + (size_t)row * E_;
    float s = 0.f;
#pragma unroll
    for (int p = 0; p < 4; ++p) {
        float4 v = *(const float4*)(src + p * 256 + lane * 4);
        ushort4 h = { f2bf(v.x), f2bf(v.y), f2bf(v.z), f2bf(v.w) };
        float a = bf2f(h.x), b = bf2f(h.y), c = bf2f(h.z), d = bf2f(h.w);
        s += a * a + b * b + c * c + d * d;
        *(ushort4*)(dst + p * 256 + lane * 4) = h;
    }
#pragma unroll
    for (int off = 32; off > 0; off >>= 1) s += __shfl_xor(s, off);
    if (lane == 0) xy2[row] = s;
}

// ---------------------------------------------------------------------------
// Pass 2: bf16 GEMM + distance epilogue. Double-buffered LDS, global_load_lds(16B),
// 2-phase schedule: issue stage t+1, compute stage t, one barrier per stage.
__global__ __launch_bounds__(256) void dist_gemm_bf(const unsigned short* __restrict__ Abf,
                                                    const unsigned short* __restrict__ Bbf,
                                                    const float* __restrict__ x2g,
                                                    const float* __restrict__ y2g,
                                                    float* __restrict__ dist) {
    __shared__ unsigned short As[2][BM * BKS];   // 2 x 16 KB
    __shared__ unsigned short Bs[2][BN * BKS];   // 2 x 10 KB

    const int tid  = threadIdx.x;
    const int lane = tid & 63;
    const int wv   = tid >> 6;
    const int l15  = lane & 15;
    const int lh   = lane >> 4;

    // XCD-aware swizzle (6400 % 8 == 0 -> simple bijective form): each XCD gets
    // 32 consecutive m-tiles x all 25 n-tiles -> A-tile re-reads are local-L2 hits.
    const int id = blockIdx.x;
    const int sw = (id & 7) * (6400 / 8) + (id >> 3);
    const int nt = sw % 25;
    const int mt = sw / 25;

    // Per-thread staging addresses. LDS dest is linear (wave-uniform base +
    // lane*16 per HW); the swizzle comes from the inverse-permuted SOURCE column
    // c^(r&7) (rule #21 / m173 pattern).
    const unsigned short* aSrc[4];
    unsigned lOffA[4];
#pragma unroll
    for (int i = 0; i < 4; ++i) {
        int idx = i * 256 + wv * 64 + lane;
        int r = idx >> 3, c = idx & 7;
        aSrc[i]  = Abf + (size_t)(mt * BM + r) * E_ + (c ^ (r & 7)) * 8;
        lOffA[i] = (unsigned)(i * 256 + wv * 64) * 8;   // bf16-elem offset, wave-uniform
    }
    const unsigned short* bSrc[3];
    unsigned lOffB[3];
#pragma unroll
    for (int i = 0; i < 2; ++i) {
        int idx = i * 256 + wv * 64 + lane;
        int r = idx >> 3, c = idx & 7;
        bSrc[i]  = Bbf + (size_t)(nt * BN + r) * E_ + (c ^ (r & 7)) * 8;
        lOffB[i] = (unsigned)(i * 256 + wv * 64) * 8;
    }
    {   // chunks 512..639 handled by waves 0,1
        int idx = 512 + wv * 64 + lane;
        int r = idx >> 3, c = idx & 7;
        bSrc[2]  = Bbf + (size_t)(nt * BN + (r < BN ? r : 0)) * E_ + (c ^ (r & 7)) * 8;
        lOffB[2] = (unsigned)(512 + wv * 64) * 8;
    }

    f32x4 acc[2][5];
#pragma unroll
    for (int i = 0; i < 2; ++i)
#pragma unroll
        for (int j = 0; j < 5; ++j) acc[i][j] = (f32x4){0.f, 0.f, 0.f, 0.f};

    // prologue: stage 0 into buffer 0
#pragma unroll
    for (int i = 0; i < 4; ++i) GLDS16(aSrc[i], &As[0][lOffA[i]]);
#pragma unroll
    for (int i = 0; i < 2; ++i) GLDS16(bSrc[i], &Bs[0][lOffB[i]]);
    if (wv < 2) GLDS16(bSrc[2], &Bs[0][lOffB[2]]);
    __syncthreads();   // drains vmcnt(0): stage 0 resident

    int buf = 0;
    for (int t = 0; t < NSTAGE; ++t) {
        // issue next stage's loads into the other buffer (fly under MFMA)
        if (t + 1 < NSTAGE) {
            const size_t ko = (size_t)(t + 1) * BKS;
#pragma unroll
            for (int i = 0; i < 4; ++i) GLDS16(aSrc[i] + ko, &As[buf ^ 1][lOffA[i]]);
#pragma unroll
            for (int i = 0; i < 2; ++i) GLDS16(bSrc[i] + ko, &Bs[buf ^ 1][lOffB[i]]);
            if (wv < 2) GLDS16(bSrc[2] + ko, &Bs[buf ^ 1][lOffB[2]]);
        }

        const char* Ab = (const char*)As[buf];
        const char* Bb = (const char*)Bs[buf];
#pragma unroll
        for (int kk = 0; kk < 2; ++kk) {
            const int kbyte = kk * 64 + lh * 16;
            short8 af[2];
#pragma unroll
            for (int mf = 0; mf < 2; ++mf)
                af[mf] = *(const short8*)(Ab + swz(wv * 32 + mf * 16 + l15, kbyte));
            short8 bfr[5];
#pragma unroll
            for (int nf = 0; nf < 5; ++nf)
                bfr[nf] = *(const short8*)(Bb + swz(nf * 16 + l15, kbyte));
#pragma unroll
            for (int mf = 0; mf < 2; ++mf)
#pragma unroll
                for (int nf = 0; nf < 5; ++nf)
                    acc[mf][nf] = __builtin_amdgcn_mfma_f32_16x16x32_bf16(
                        af[mf], bfr[nf], acc[mf][nf], 0, 0, 0);
        }
        // barrier drains vmcnt (next stage resident) and fences LDS reads of buf
        __syncthreads();
        buf ^= 1;
    }

    // Epilogue: d = sqrt(max(x2 + y2 - 2*xy, 0)). C/D: col=lane&15, row=(lane>>4)*4+reg
    float x2v[2][4], y2v[5];
#pragma unroll
    for (int mf = 0; mf < 2; ++mf)
#pragma unroll
        for (int rg = 0; rg < 4; ++rg)
            x2v[mf][rg] = x2g[mt * BM + wv * 32 + mf * 16 + lh * 4 + rg];
#pragma unroll
    for (int nf = 0; nf < 5; ++nf) y2v[nf] = y2g[nt * BN + nf * 16 + l15];

#pragma unroll
    for (int mf = 0; mf < 2; ++mf) {
#pragma unroll
        for (int nf = 0; nf < 5; ++nf) {
#pragma unroll
            for (int rg = 0; rg < 4; ++rg) {
                int m = mt * BM + wv * 32 + mf * 16 + lh * 4 + rg;
                int n = nt * BN + nf * 16 + l15;
                int b = m >> 9;
                int s = m & (S_ - 1);
                int p = n / K_;
                int k = n - p * K_;
                float d2 = x2v[mf][rg] + y2v[nf] - 2.f * acc[mf][nf][rg];
                dist[(((size_t)b * P_ + p) * S_ + s) * K_ + k] = sqrtf(fmaxf(d2, 0.f));
            }
        }
    }
}

// ---------------------------------------------------------------------------
// Fallback (round-3 kernel) if ws_size can't hold the bf16 copies.
__global__ __launch_bounds__(256) void dist_mfma_fb(const float* __restrict__ emb,
                                                    const float* __restrict__ proto,
                                                    float* __restrict__ dist) {
    __shared__ short As[BM * BKS];
    __shared__ short Bs[BN * BKS];
    __shared__ float x2s[BM];
    __shared__ float y2s[BN];

    const int tid  = threadIdx.x;
    const int lane = tid & 63;
    const int wv   = tid >> 6;
    const int l15  = lane & 15;
    const int lh   = lane >> 4;

    const int id = blockIdx.x;
    const int sw = (id & 7) * (6400 / 8) + (id >> 3);
    const int nt = sw % 25;
    const int mt = sw / 25;

    const float* Ab = emb + (size_t)mt * BM * E_ + (size_t)(tid >> 4) * E_ + (tid & 15) * 4;
    const float* Bb = proto + (size_t)nt * BN * E_ + (size_t)(tid >> 4) * E_ + (tid & 15) * 4;

    f32x4 acc[2][5];
#pragma unroll
    for (int i = 0; i < 2; ++i)
#pragma unroll
        for (int j = 0; j < 5; ++j) acc[i][j] = (f32x4){0.f, 0.f, 0.f, 0.f};

    float x2p[8], y2p[5];
#pragma unroll
    for (int i = 0; i < 8; ++i) x2p[i] = 0.f;
#pragma unroll
    for (int i = 0; i < 5; ++i) y2p[i] = 0.f;

    float4 pa[8], pb[5];
#pragma unroll
    for (int i = 0; i < 8; ++i) pa[i] = *(const float4*)(Ab + (size_t)i * 16 * E_);
#pragma unroll
    for (int i = 0; i < 5; ++i) pb[i] = *(const float4*)(Bb + (size_t)i * 16 * E_);

    for (int t = 0; t < NSTAGE; ++t) {
        ushort4 ca[8];
#pragma unroll
        for (int i = 0; i < 8; ++i) {
            float4 v = pa[i];
            x2p[i] += v.x * v.x + v.y * v.y + v.z * v.z + v.w * v.w;
            ca[i] = (ushort4){ f2bf(v.x), f2bf(v.y), f2bf(v.z), f2bf(v.w) };
        }
        ushort4 cb[5];
#pragma unroll
        for (int i = 0; i < 5; ++i) {
            float4 v = pb[i];
            y2p[i] += v.x * v.x + v.y * v.y + v.z * v.z + v.w * v.w;
            cb[i] = (ushort4){ f2bf(v.x), f2bf(v.y), f2bf(v.z), f2bf(v.w) };
        }
        __syncthreads();
#pragma unroll
        for (int i = 0; i < 8; ++i) {
            int idx = i * 256 + tid;
            *(ushort4*)((char*)As + swz(idx >> 4, (idx & 15) * 8)) = ca[i];
        }
#pragma unroll
        for (int i = 0; i < 5; ++i) {
            int idx = i * 256 + tid;
            *(ushort4*)((char*)Bs + swz(idx >> 4, (idx & 15) * 8)) = cb[i];
        }
        __syncthreads();
        if (t + 1 < NSTAGE) {
            const float* An = Ab + (size_t)(t + 1) * BKS;
            const float* Bn = Bb + (size_t)(t + 1) * BKS;
#pragma unroll
            for (int i = 0; i < 8; ++i) pa[i] = *(const float4*)(An + (size_t)i * 16 * E_);
#pragma unroll
            for (int i = 0; i < 5; ++i) pb[i] = *(const float4*)(Bn + (size_t)i * 16 * E_);
        }
#pragma unroll
        for (int kk = 0; kk < 2; ++kk) {
            const int kbyte = kk * 64 + lh * 16;
            short8 af[2];
#pragma unroll
            for (int mf = 0; mf < 2; ++mf)
                af[mf] = *(const short8*)((const char*)As + swz(wv * 32 + mf * 16 + l15, kbyte));
            short8 bfr[5];
#pragma unroll
            for (int nf = 0; nf < 5; ++nf)
                bfr[nf] = *(const short8*)((const char*)Bs + swz(nf * 16 + l15, kbyte));
#pragma unroll
            for (int mf = 0; mf < 2; ++mf)
#pragma unroll
                for (int nf = 0; nf < 5; ++nf)
                    acc[mf][nf] = __builtin_amdgcn_mfma_f32_16x16x32_bf16(
                        af[mf], bfr[nf], acc[mf][nf], 0, 0, 0);
        }
    }

#pragma unroll
    for (int i = 0; i < 8; ++i) {
        float v = x2p[i];
        v += __shfl_xor(v, 1); v += __shfl_xor(v, 2);
        v += __shfl_xor(v, 4); v += __shfl_xor(v, 8);
        if (l15 == 0) x2s[16 * i + (tid >> 4)] = v;
    }
#pragma unroll
    for (int i = 0; i < 5; ++i) {
        float v = y2p[i];
        v += __shfl_xor(v, 1); v += __shfl_xor(v, 2);
        v += __shfl_xor(v, 4); v += __shfl_xor(v, 8);
        if (l15 == 0) y2s[16 * i + (tid >> 4)] = v;
    }
    __syncthreads();

#pragma unroll
    for (int mf = 0; mf < 2; ++mf) {
#pragma unroll
        for (int nf = 0; nf < 5; ++nf) {
#pragma unroll
            for (int rg = 0; rg < 4; ++rg) {
                int ml = wv * 32 + mf * 16 + lh * 4 + rg;
                int nl = nf * 16 + l15;
                int m = mt * BM + ml;
                int n = nt * BN + nl;
                int b = m >> 9;
                int s = m & (S_ - 1);
                int p = n / K_;
                int k = n - p * K_;
                float d2 = x2s[ml] + y2s[nl] - 2.f * acc[mf][nf][rg];
                dist[(((size_t)b * P_ + p) * S_ + s) * K_ + k] = sqrtf(fmaxf(d2, 0.f));
            }
        }
    }
}

// ---------------------------------------------------------------------------
// One block per (b,p): min over s for each k, then mean over k.
__global__ __launch_bounds__(256) void min_mean(const float* __restrict__ dist,
                                                float* __restrict__ pd) {
    const int p = blockIdx.x;
    const int b = blockIdx.y;
    const float* dp = dist + ((size_t)b * P_ + p) * (size_t)(S_ * K_);
    const int tid = threadIdx.x;

    const float4* base = (const float4*)(dp + (size_t)tid * 20);
    float4 q0 = base[0], q1 = base[1], q2 = base[2], q3 = base[3], q4 = base[4];

    float mn[K_];
    mn[0] = fminf(q0.x, q2.z); mn[1] = fminf(q0.y, q2.w);
    mn[2] = fminf(q0.z, q3.x); mn[3] = fminf(q0.w, q3.y);
    mn[4] = fminf(q1.x, q3.z); mn[5] = fminf(q1.y, q3.w);
    mn[6] = fminf(q1.z, q4.x); mn[7] = fminf(q1.w, q4.y);
    mn[8] = fminf(q2.x, q4.z); mn[9] = fminf(q2.y, q4.w);

#pragma unroll
    for (int k = 0; k < K_; ++k) {
#pragma unroll
        for (int off = 32; off > 0; off >>= 1)
            mn[k] = fminf(mn[k], __shfl_xor(mn[k], off));
    }

    __shared__ float red[4][K_];
    if ((tid & 63) == 0) {
#pragma unroll
        for (int k = 0; k < K_; ++k) red[tid >> 6][k] = mn[k];
    }
    __syncthreads();
    if (tid == 0) {
        float sum = 0.f;
#pragma unroll
        for (int k = 0; k < K_; ++k)
            sum += fminf(fminf(red[0][k], red[1][k]), fminf(red[2][k], red[3][k]));
        pd[b * P_ + p] = sum * (1.0f / K_);
    }
}

__global__ void fc_kernel(const float* __restrict__ pd, const float* __restrict__ fc,
                          float* __restrict__ cls) {
    int tid = threadIdx.x;
    if (tid < B_ * C_) {
        int b = tid / C_;
        int c = tid % C_;
        float s = 0.f;
        for (int p = 0; p < P_; ++p) s += pd[b * P_ + p] * fc[c * P_ + p];
        cls[b * C_ + c] = s;
    }
}

extern "C" void kernel_launch(void* const* d_in, const int* in_sizes, int n_in,
                              void* d_out, int out_size, void* d_ws, size_t ws_size,
                              hipStream_t stream) {
    const float* emb   = (const float*)d_in[0];   // [64,512,1024]
    const float* proto = (const float*)d_in[1];   // [200,10,1024]
    const float* fc    = (const float*)d_in[2];   // [3,200]
    float* out = (float*)d_out;

    float* pd   = out;                                                // [64,200]
    float* dist = out + (size_t)B_ * P_;                              // [64,200,512,10]
    float* cls  = out + (size_t)B_ * P_ + (size_t)B_ * P_ * S_ * K_;  // [64,3]

    const size_t bf_bytes = (size_t)NROWS_T * E_ * 2;                 // 71,204,864
    const size_t ws_need  = bf_bytes + (size_t)NROWS_T * 4;           // + 139 KB

    if (ws_size >= ws_need) {
        unsigned short* bf = (unsigned short*)d_ws;
        float* xy2 = (float*)((char*)d_ws + bf_bytes);
        preconvert<<<NROWS_T / 4, 256, 0, stream>>>(emb, proto, bf, xy2);
        dist_gemm_bf<<<6400, 256, 0, stream>>>(bf, bf + (size_t)NROWS_A * E_,
                                               xy2, xy2 + NROWS_A, dist);
    } else {
        dist_mfma_fb<<<6400, 256, 0, stream>>>(emb, proto, dist);
    }
    min_mean<<<dim3(P_, B_), 256, 0, stream>>>(dist, pd);
    fc_kernel<<<1, 256, 0, stream>>>(pd, fc, cls);
}

// Round 5
// 309.791 us; speedup vs baseline: 8.2472x; 1.1162x over previous
//
#include <hip/hip_runtime.h>
#include <hip/hip_bf16.h>

#define B_ 64
#define S_ 512
#define E_ 1024
#define P_ 200
#define K_ 10
#define C_ 3

#define BM 128
#define BN 80
#define BKS 64                 // K elements per LDS stage
#define NSTAGE (E_ / BKS)      // 16
#define NROWS_A (B_ * S_)      // 32768
#define NROWS_B (P_ * K_)      // 2000
#define NROWS_T (NROWS_A + NROWS_B)  // 34768
#define NMT 256                // m-tiles
#define NNT 25                 // n-tiles

typedef __attribute__((ext_vector_type(8))) short short8;
typedef __attribute__((ext_vector_type(4))) float f32x4;

__device__ __forceinline__ float bf2f(unsigned short u) {
    unsigned int x = ((unsigned int)u) << 16;
    return __uint_as_float(x);
}
__device__ __forceinline__ unsigned short f2bf(float f) {
    __hip_bfloat16 h = __float2bfloat16(f);
    unsigned short u;
    __builtin_memcpy(&u, &h, 2);
    return u;
}

// Read-side swizzle: row-major [row][64] bf16 (row stride 128 B); logical 16B
// chunk kbyte>>4 lives at physical slot (kbyte>>4)^(row&7). Involution with the
// pre-swizzled staging SOURCE column (rule #21 / m173 pattern).
__device__ __forceinline__ int swz(int row, int kbyte) {
    return (row * (BKS * 2) + kbyte) ^ ((row & 7) << 4);
}

#define GLDS16(gsrc, ldst)                                                              \
    __builtin_amdgcn_global_load_lds((const __attribute__((address_space(1))) unsigned int*)(gsrc), \
                                     (__attribute__((address_space(3))) unsigned int*)(ldst), 16, 0, 0)

// ---------------------------------------------------------------------------
// Pass 1: f32 -> bf16 for emb / proto + per-row |.|^2 of the rounded values.
__global__ __launch_bounds__(256) void preconvert(const float* __restrict__ emb,
                                                  const float* __restrict__ proto,
                                                  unsigned short* __restrict__ bf,
                                                  float* __restrict__ xy2) {
    const int row  = blockIdx.x * 4 + (threadIdx.x >> 6);
    const int lane = threadIdx.x & 63;
    const float* src = (row < NROWS_A) ? emb + (size_t)row * E_
                                       : proto + (size_t)(row - NROWS_A) * E_;
    unsigned short* dst = bf + (size_t)row * E_;
    float s = 0.f;
#pragma unroll
    for (int p = 0; p < 4; ++p) {
        float4 v = *(const float4*)(src + p * 256 + lane * 4);
        ushort4 h = { f2bf(v.x), f2bf(v.y), f2bf(v.z), f2bf(v.w) };
        float a = bf2f(h.x), b = bf2f(h.y), c = bf2f(h.z), d = bf2f(h.w);
        s += a * a + b * b + c * c + d * d;
        *(ushort4*)(dst + p * 256 + lane * 4) = h;
    }
#pragma unroll
    for (int off = 32; off > 0; off >>= 1) s += __shfl_xor(s, off);
    if (lane == 0) xy2[row] = s;
}

// ---------------------------------------------------------------------------
// Pass 2: bf16 GEMM + distance epilogue + fused per-block s-min.
// 3-buffer LDS, global_load_lds(16B), counted vmcnt (T3+T4), raw s_barrier.
__global__ __launch_bounds__(256) void dist_gemm_bf(const unsigned short* __restrict__ Abf,
                                                    const unsigned short* __restrict__ Bbf,
                                                    const float* __restrict__ x2g,
                                                    const float* __restrict__ y2g,
                                                    float* __restrict__ dist,
                                                    float* __restrict__ ws_min) {
    __shared__ unsigned short As[3][BM * BKS];   // 3 x 16 KB
    __shared__ unsigned short Bs[3][BN * BKS];   // 3 x 10 KB
    __shared__ float red[4][BN];                 // 1.25 KB  (total 81152 B -> 2 blocks/CU)

    const int tid  = threadIdx.x;
    const int lane = tid & 63;
    const int wv   = tid >> 6;
    const int l15  = lane & 15;
    const int lh   = lane >> 4;

    // XCD-aware swizzle (6400 % 8 == 0): each XCD gets 32 consecutive m-tiles
    // x all 25 n-tiles -> A-tile re-reads are local-L2 hits.
    const int id = blockIdx.x;
    const int sw = (id & 7) * (6400 / 8) + (id >> 3);
    const int nt = sw % NNT;
    const int mt = sw / NNT;

    // Staging addresses (identical math to the verified round-4 kernel).
    // LDS dest linear (wave-uniform base + lane*16); swizzle via inverse-permuted
    // SOURCE column c^(r&7).
    const unsigned short* aSrc[4];
    unsigned lOffA[4];
#pragma unroll
    for (int i = 0; i < 4; ++i) {
        int idx = i * 256 + wv * 64 + lane;
        int r = idx >> 3, c = idx & 7;
        aSrc[i]  = Abf + (size_t)(mt * BM + r) * E_ + (c ^ (r & 7)) * 8;
        lOffA[i] = (unsigned)(i * 256 + wv * 64) * 8;
    }
    const unsigned short* bSrc[3];
    unsigned lOffB[3];
#pragma unroll
    for (int i = 0; i < 2; ++i) {
        int idx = i * 256 + wv * 64 + lane;
        int r = idx >> 3, c = idx & 7;
        bSrc[i]  = Bbf + (size_t)(nt * BN + r) * E_ + (c ^ (r & 7)) * 8;
        lOffB[i] = (unsigned)(i * 256 + wv * 64) * 8;
    }
    {
        int idx = 512 + wv * 64 + lane;
        int r = idx >> 3, c = idx & 7;
        bSrc[2]  = Bbf + (size_t)(nt * BN + (r < BN ? r : 0)) * E_ + (c ^ (r & 7)) * 8;
        lOffB[2] = (unsigned)(512 + wv * 64) * 8;
    }

    f32x4 acc[2][5];
#pragma unroll
    for (int i = 0; i < 2; ++i)
#pragma unroll
        for (int j = 0; j < 5; ++j) acc[i][j] = (f32x4){0.f, 0.f, 0.f, 0.f};

    // Per-wave loads per stage: waves 0,1 -> 7 instrs; waves 2,3 -> 6.
#define ISSUE(tt, bb)                                                          \
    do {                                                                       \
        const size_t ko_ = (size_t)(tt) * BKS;                                 \
        _Pragma("unroll")                                                      \
        for (int i_ = 0; i_ < 4; ++i_) GLDS16(aSrc[i_] + ko_, &As[bb][lOffA[i_]]); \
        _Pragma("unroll")                                                      \
        for (int i_ = 0; i_ < 2; ++i_) GLDS16(bSrc[i_] + ko_, &Bs[bb][lOffB[i_]]); \
        if (wv < 2) GLDS16(bSrc[2] + ko_, &Bs[bb][lOffB[2]]);                  \
    } while (0)

#define COMPUTE(bb)                                                            \
    do {                                                                       \
        const char* Ab_ = (const char*)As[bb];                                 \
        const char* Bb_ = (const char*)Bs[bb];                                 \
        _Pragma("unroll")                                                      \
        for (int kk = 0; kk < 2; ++kk) {                                       \
            const int kbyte = kk * 64 + lh * 16;                               \
            short8 af[2];                                                      \
            _Pragma("unroll")                                                  \
            for (int mf = 0; mf < 2; ++mf)                                     \
                af[mf] = *(const short8*)(Ab_ + swz(wv * 32 + mf * 16 + l15, kbyte)); \
            short8 bfr[5];                                                     \
            _Pragma("unroll")                                                  \
            for (int nf = 0; nf < 5; ++nf)                                     \
                bfr[nf] = *(const short8*)(Bb_ + swz(nf * 16 + l15, kbyte));   \
            _Pragma("unroll")                                                  \
            for (int mf = 0; mf < 2; ++mf)                                     \
                _Pragma("unroll")                                              \
                for (int nf = 0; nf < 5; ++nf)                                 \
                    acc[mf][nf] = __builtin_amdgcn_mfma_f32_16x16x32_bf16(     \
                        af[mf], bfr[nf], acc[mf][nf], 0, 0, 0);                \
        }                                                                      \
    } while (0)

    // prologue: stages 0,1 in flight
    ISSUE(0, 0);
    ISSUE(1, 1);

    // steady state: wait(counted) -> barrier -> issue t+2 -> compute t
    int bi = 0;
#pragma unroll 3
    for (int t = 0; t < NSTAGE - 1; ++t) {
        if (wv < 2) { asm volatile("s_waitcnt vmcnt(7)" ::: "memory"); }
        else        { asm volatile("s_waitcnt vmcnt(6)" ::: "memory"); }
        __builtin_amdgcn_sched_barrier(0);
        __builtin_amdgcn_s_barrier();
        if (t + 2 < NSTAGE) {
            int bw = bi + 2; if (bw >= 3) bw -= 3;
            ISSUE(t + 2, bw);
        }
        COMPUTE(bi);
        if (++bi == 3) bi = 0;
    }
    // final stage: nothing issued after it -> drain
    asm volatile("s_waitcnt vmcnt(0)" ::: "memory");
    __builtin_amdgcn_sched_barrier(0);
    __builtin_amdgcn_s_barrier();
    COMPUTE(bi);

    // Epilogue: d = sqrt(max(x2 + y2 - 2*xy, 0)); write dist; track per-col min.
    // C/D layout: col = lane&15, row = (lane>>4)*4 + reg.
    float x2v[2][4], y2v[5];
#pragma unroll
    for (int mf = 0; mf < 2; ++mf)
#pragma unroll
        for (int rg = 0; rg < 4; ++rg)
            x2v[mf][rg] = x2g[mt * BM + wv * 32 + mf * 16 + lh * 4 + rg];
#pragma unroll
    for (int nf = 0; nf < 5; ++nf) y2v[nf] = y2g[nt * BN + nf * 16 + l15];

    float mloc[5];
#pragma unroll
    for (int nf = 0; nf < 5; ++nf) mloc[nf] = 3.4e38f;

#pragma unroll
    for (int mf = 0; mf < 2; ++mf) {
#pragma unroll
        for (int nf = 0; nf < 5; ++nf) {
#pragma unroll
            for (int rg = 0; rg < 4; ++rg) {
                int m = mt * BM + wv * 32 + mf * 16 + lh * 4 + rg;
                int n = nt * BN + nf * 16 + l15;
                int b = m >> 9;
                int s = m & (S_ - 1);
                int p = n / K_;
                int k = n - p * K_;
                float d2 = x2v[mf][rg] + y2v[nf] - 2.f * acc[mf][nf][rg];
                float d  = sqrtf(fmaxf(d2, 0.f));
                dist[(((size_t)b * P_ + p) * S_ + s) * K_ + k] = d;
                mloc[nf] = fminf(mloc[nf], d);
            }
        }
    }

    // Reduce min over the wave's 32 rows (lanes differing in lh hold other rows)
#pragma unroll
    for (int nf = 0; nf < 5; ++nf) {
        mloc[nf] = fminf(mloc[nf], __shfl_xor(mloc[nf], 16));
        mloc[nf] = fminf(mloc[nf], __shfl_xor(mloc[nf], 32));
    }
    if (lane < 16) {
#pragma unroll
        for (int nf = 0; nf < 5; ++nf) red[wv][nf * 16 + lane] = mloc[nf];
    }
    __syncthreads();
    if (tid < BN) {
        float v = fminf(fminf(red[0][tid], red[1][tid]), fminf(red[2][tid], red[3][tid]));
        ws_min[(size_t)mt * NROWS_B + nt * BN + tid] = v;
    }
#undef ISSUE
#undef COMPUTE
}

// ---------------------------------------------------------------------------
// Final: min over 4 m-subtiles, mean over k -> pd; then FC. One block per b.
__global__ __launch_bounds__(256) void mean_fc(const float* __restrict__ ws_min,
                                               const float* __restrict__ fcw,
                                               float* __restrict__ pd,
                                               float* __restrict__ cls) {
    const int b = blockIdx.x;
    const int t = threadIdx.x;
    __shared__ float pds[P_];
    if (t < P_) {
        float sum = 0.f;
#pragma unroll
        for (int k = 0; k < K_; ++k) {
            float m = 3.4e38f;
#pragma unroll
            for (int st = 0; st < 4; ++st)
                m = fminf(m, ws_min[(size_t)(b * 4 + st) * NROWS_B + t * K_ + k]);
            sum += m;
        }
        float v = sum * (1.0f / K_);
        pd[b * P_ + t] = v;
        pds[t] = v;
    }
    __syncthreads();
    if (t < C_) {
        float s = 0.f;
        for (int p = 0; p < P_; ++p) s += pds[p] * fcw[t * P_ + p];
        cls[b * C_ + t] = s;
    }
}

// ---------------------------------------------------------------------------
// Fallback path (no-workspace): round-3 fused kernel + min_mean + fc.
__global__ __launch_bounds__(256) void dist_mfma_fb(const float* __restrict__ emb,
                                                    const float* __restrict__ proto,
                                                    float* __restrict__ dist) {
    __shared__ short As[BM * BKS];
    __shared__ short Bs[BN * BKS];
    __shared__ float x2s[BM];
    __shared__ float y2s[BN];

    const int tid  = threadIdx.x;
    const int lane = tid & 63;
    const int wv   = tid >> 6;
    const int l15  = lane & 15;
    const int lh   = lane >> 4;

    const int id = blockIdx.x;
    const int sw = (id & 7) * (6400 / 8) + (id >> 3);
    const int nt = sw % NNT;
    const int mt = sw / NNT;

    const float* Ab = emb + (size_t)mt * BM * E_ + (size_t)(tid >> 4) * E_ + (tid & 15) * 4;
    const float* Bb = proto + (size_t)nt * BN * E_ + (size_t)(tid >> 4) * E_ + (tid & 15) * 4;

    f32x4 acc[2][5];
#pragma unroll
    for (int i = 0; i < 2; ++i)
#pragma unroll
        for (int j = 0; j < 5; ++j) acc[i][j] = (f32x4){0.f, 0.f, 0.f, 0.f};

    float x2p[8], y2p[5];
#pragma unroll
    for (int i = 0; i < 8; ++i) x2p[i] = 0.f;
#pragma unroll
    for (int i = 0; i < 5; ++i) y2p[i] = 0.f;

    float4 pa[8], pb[5];
#pragma unroll
    for (int i = 0; i < 8; ++i) pa[i] = *(const float4*)(Ab + (size_t)i * 16 * E_);
#pragma unroll
    for (int i = 0; i < 5; ++i) pb[i] = *(const float4*)(Bb + (size_t)i * 16 * E_);

    for (int t = 0; t < NSTAGE; ++t) {
        ushort4 ca[8];
#pragma unroll
        for (int i = 0; i < 8; ++i) {
            float4 v = pa[i];
            x2p[i] += v.x * v.x + v.y * v.y + v.z * v.z + v.w * v.w;
            ca[i] = (ushort4){ f2bf(v.x), f2bf(v.y), f2bf(v.z), f2bf(v.w) };
        }
        ushort4 cb[5];
#pragma unroll
        for (int i = 0; i < 5; ++i) {
            float4 v = pb[i];
            y2p[i] += v.x * v.x + v.y * v.y + v.z * v.z + v.w * v.w;
            cb[i] = (ushort4){ f2bf(v.x), f2bf(v.y), f2bf(v.z), f2bf(v.w) };
        }
        __syncthreads();
#pragma unroll
        for (int i = 0; i < 8; ++i) {
            int idx = i * 256 + tid;
            *(ushort4*)((char*)As + swz(idx >> 4, (idx & 15) * 8)) = ca[i];
        }
#pragma unroll
        for (int i = 0; i < 5; ++i) {
            int idx = i * 256 + tid;
            *(ushort4*)((char*)Bs + swz(idx >> 4, (idx & 15) * 8)) = cb[i];
        }
        __syncthreads();
        if (t + 1 < NSTAGE) {
            const float* An = Ab + (size_t)(t + 1) * BKS;
            const float* Bn = Bb + (size_t)(t + 1) * BKS;
#pragma unroll
            for (int i = 0; i < 8; ++i) pa[i] = *(const float4*)(An + (size_t)i * 16 * E_);
#pragma unroll
            for (int i = 0; i < 5; ++i) pb[i] = *(const float4*)(Bn + (size_t)i * 16 * E_);
        }
#pragma unroll
        for (int kk = 0; kk < 2; ++kk) {
            const int kbyte = kk * 64 + lh * 16;
            short8 af[2];
#pragma unroll
            for (int mf = 0; mf < 2; ++mf)
                af[mf] = *(const short8*)((const char*)As + swz(wv * 32 + mf * 16 + l15, kbyte));
            short8 bfr[5];
#pragma unroll
            for (int nf = 0; nf < 5; ++nf)
                bfr[nf] = *(const short8*)((const char*)Bs + swz(nf * 16 + l15, kbyte));
#pragma unroll
            for (int mf = 0; mf < 2; ++mf)
#pragma unroll
                for (int nf = 0; nf < 5; ++nf)
                    acc[mf][nf] = __builtin_amdgcn_mfma_f32_16x16x32_bf16(
                        af[mf], bfr[nf], acc[mf][nf], 0, 0, 0);
        }
    }

#pragma unroll
    for (int i = 0; i < 8; ++i) {
        float v = x2p[i];
        v += __shfl_xor(v, 1); v += __shfl_xor(v, 2);
        v += __shfl_xor(v, 4); v += __shfl_xor(v, 8);
        if (l15 == 0) x2s[16 * i + (tid >> 4)] = v;
    }
#pragma unroll
    for (int i = 0; i < 5; ++i) {
        float v = y2p[i];
        v += __shfl_xor(v, 1); v += __shfl_xor(v, 2);
        v += __shfl_xor(v, 4); v += __shfl_xor(v, 8);
        if (l15 == 0) y2s[16 * i + (tid >> 4)] = v;
    }
    __syncthreads();

#pragma unroll
    for (int mf = 0; mf < 2; ++mf) {
#pragma unroll
        for (int nf = 0; nf < 5; ++nf) {
#pragma unroll
            for (int rg = 0; rg < 4; ++rg) {
                int ml = wv * 32 + mf * 16 + lh * 4 + rg;
                int nl = nf * 16 + l15;
                int m = mt * BM + ml;
                int n = nt * BN + nl;
                int b = m >> 9;
                int s = m & (S_ - 1);
                int p = n / K_;
                int k = n - p * K_;
                float d2 = x2s[ml] + y2s[nl] - 2.f * acc[mf][nf][rg];
                dist[(((size_t)b * P_ + p) * S_ + s) * K_ + k] = sqrtf(fmaxf(d2, 0.f));
            }
        }
    }
}

__global__ __launch_bounds__(256) void min_mean(const float* __restrict__ dist,
                                                float* __restrict__ pd) {
    const int p = blockIdx.x;
    const int b = blockIdx.y;
    const float* dp = dist + ((size_t)b * P_ + p) * (size_t)(S_ * K_);
    const int tid = threadIdx.x;

    const float4* base = (const float4*)(dp + (size_t)tid * 20);
    float4 q0 = base[0], q1 = base[1], q2 = base[2], q3 = base[3], q4 = base[4];

    float mn[K_];
    mn[0] = fminf(q0.x, q2.z); mn[1] = fminf(q0.y, q2.w);
    mn[2] = fminf(q0.z, q3.x); mn[3] = fminf(q0.w, q3.y);
    mn[4] = fminf(q1.x, q3.z); mn[5] = fminf(q1.y, q3.w);
    mn[6] = fminf(q1.z, q4.x); mn[7] = fminf(q1.w, q4.y);
    mn[8] = fminf(q2.x, q4.z); mn[9] = fminf(q2.y, q4.w);

#pragma unroll
    for (int k = 0; k < K_; ++k) {
#pragma unroll
        for (int off = 32; off > 0; off >>= 1)
            mn[k] = fminf(mn[k], __shfl_xor(mn[k], off));
    }

    __shared__ float red[4][K_];
    if ((tid & 63) == 0) {
#pragma unroll
        for (int k = 0; k < K_; ++k) red[tid >> 6][k] = mn[k];
    }
    __syncthreads();
    if (tid == 0) {
        float sum = 0.f;
#pragma unroll
        for (int k = 0; k < K_; ++k)
            sum += fminf(fminf(red[0][k], red[1][k]), fminf(red[2][k], red[3][k]));
        pd[b * P_ + p] = sum * (1.0f / K_);
    }
}

__global__ void fc_kernel(const float* __restrict__ pd, const float* __restrict__ fc,
                          float* __restrict__ cls) {
    int tid = threadIdx.x;
    if (tid < B_ * C_) {
        int b = tid / C_;
        int c = tid % C_;
        float s = 0.f;
        for (int p = 0; p < P_; ++p) s += pd[b * P_ + p] * fc[c * P_ + p];
        cls[b * C_ + c] = s;
    }
}

extern "C" void kernel_launch(void* const* d_in, const int* in_sizes, int n_in,
                              void* d_out, int out_size, void* d_ws, size_t ws_size,
                              hipStream_t stream) {
    const float* emb   = (const float*)d_in[0];   // [64,512,1024]
    const float* proto = (const float*)d_in[1];   // [200,10,1024]
    const float* fc    = (const float*)d_in[2];   // [3,200]
    float* out = (float*)d_out;

    float* pd   = out;                                                // [64,200]
    float* dist = out + (size_t)B_ * P_;                              // [64,200,512,10]
    float* cls  = out + (size_t)B_ * P_ + (size_t)B_ * P_ * S_ * K_;  // [64,3]

    const size_t bf_bytes  = (size_t)NROWS_T * E_ * 2;                // 71,204,864
    const size_t xy2_bytes = (size_t)NROWS_T * 4;                     // 139,072
    const size_t min_bytes = (size_t)NMT * NROWS_B * 4;               // 2,048,000
    const size_t ws_need   = bf_bytes + xy2_bytes + min_bytes;

    if (ws_size >= ws_need) {
        unsigned short* bf = (unsigned short*)d_ws;
        float* xy2    = (float*)((char*)d_ws + bf_bytes);
        float* ws_min = (float*)((char*)d_ws + bf_bytes + xy2_bytes);
        preconvert<<<NROWS_T / 4, 256, 0, stream>>>(emb, proto, bf, xy2);
        dist_gemm_bf<<<6400, 256, 0, stream>>>(bf, bf + (size_t)NROWS_A * E_,
                                               xy2, xy2 + NROWS_A, dist, ws_min);
        mean_fc<<<B_, 256, 0, stream>>>(ws_min, fc, pd, cls);
    } else {
        dist_mfma_fb<<<6400, 256, 0, stream>>>(emb, proto, dist);
        min_mean<<<dim3(P_, B_), 256, 0, stream>>>(dist, pd);
        fc_kernel<<<1, 256, 0, stream>>>(pd, fc, cls);
    }
}

// Round 6
// 287.520 us; speedup vs baseline: 8.8860x; 1.0775x over previous
//
#include <hip/hip_runtime.h>
#include <hip/hip_bf16.h>

#define B_ 64
#define S_ 512
#define E_ 1024
#define P_ 200
#define K_ 10
#define C_ 3

#define BM 128
#define BN 128
#define BKS 64                 // K elements per LDS stage
#define NSTAGE (E_ / BKS)      // 16
#define NROWS_A (B_ * S_)      // 32768
#define NROWS_B (P_ * K_)      // 2000
#define NB_PAD 2048            // padded N
#define NROWS_P (NROWS_A + NB_PAD)   // 34816 rows in bf buffer
#define NMT 256                // m-tiles (32768/128)
#define NNT 16                 // n-tiles (2048/128)

typedef __attribute__((ext_vector_type(8))) short short8;
typedef __attribute__((ext_vector_type(4))) float f32x4;
typedef __attribute__((ext_vector_type(16))) float f32x16;

__device__ __forceinline__ float bf2f(unsigned short u) {
    unsigned int x = ((unsigned int)u) << 16;
    return __uint_as_float(x);
}
__device__ __forceinline__ unsigned short f2bf(float f) {
    __hip_bfloat16 h = __float2bfloat16(f);
    unsigned short u;
    __builtin_memcpy(&u, &h, 2);
    return u;
}

// Read-side swizzle: row-major [row][64] bf16 (row stride 128 B); logical 16B
// chunk kbyte>>4 lives at physical slot (kbyte>>4)^(row&7). Involution with the
// pre-swizzled staging SOURCE column (rule #21 / m173 pattern).
__device__ __forceinline__ int swz(int row, int kbyte) {
    return (row * (BKS * 2) + kbyte) ^ ((row & 7) << 4);
}

#define GLDS16(gsrc, ldst)                                                              \
    __builtin_amdgcn_global_load_lds((const __attribute__((address_space(1))) unsigned int*)(gsrc), \
                                     (__attribute__((address_space(3))) unsigned int*)(ldst), 16, 0, 0)

// ---------------------------------------------------------------------------
// Pass 1: f32 -> bf16 for emb (rows 0..32767), proto (rows 32768..34767),
// zero-pad (rows 34768..34815); per-row |.|^2 of rounded values.
__global__ __launch_bounds__(256) void preconvert(const float* __restrict__ emb,
                                                  const float* __restrict__ proto,
                                                  unsigned short* __restrict__ bf,
                                                  float* __restrict__ xy2) {
    const int row  = blockIdx.x * 4 + (threadIdx.x >> 6);
    const int lane = threadIdx.x & 63;
    unsigned short* dst = bf + (size_t)row * E_;

    if (row >= NROWS_A + NROWS_B) {   // pad rows: zeros
        ushort4 z = {0, 0, 0, 0};
#pragma unroll
        for (int p = 0; p < 4; ++p) *(ushort4*)(dst + p * 256 + lane * 4) = z;
        if (lane == 0) xy2[row] = 0.f;
        return;
    }
    const float* src = (row < NROWS_A) ? emb + (size_t)row * E_
                                       : proto + (size_t)(row - NROWS_A) * E_;
    float s = 0.f;
#pragma unroll
    for (int p = 0; p < 4; ++p) {
        float4 v = *(const float4*)(src + p * 256 + lane * 4);
        ushort4 h = { f2bf(v.x), f2bf(v.y), f2bf(v.z), f2bf(v.w) };
        float a = bf2f(h.x), b = bf2f(h.y), c = bf2f(h.z), d = bf2f(h.w);
        s += a * a + b * b + c * c + d * d;
        *(ushort4*)(dst + p * 256 + lane * 4) = h;
    }
#pragma unroll
    for (int off = 32; off > 0; off >>= 1) s += __shfl_xor(s, off);
    if (lane == 0) xy2[row] = s;
}

// ---------------------------------------------------------------------------
// Pass 2: bf16 GEMM (32x32x16 MFMA) + distance epilogue + fused per-block s-min.
// 128x128 tile, 4 waves as 2m x 2n, each wave 64x64 = 2x2 32-frags.
// Double-buffered LDS, global_load_lds(16B), issue-next -> compute -> barrier.
__global__ __launch_bounds__(256) void dist_gemm_bf(const unsigned short* __restrict__ Abf,
                                                    const unsigned short* __restrict__ Bbf,
                                                    const float* __restrict__ x2g,
                                                    const float* __restrict__ y2g,
                                                    float* __restrict__ dist,
                                                    float* __restrict__ ws_min) {
    __shared__ unsigned short As[2][BM * BKS];   // 2 x 16 KB
    __shared__ unsigned short Bs[2][BN * BKS];   // 2 x 16 KB
    __shared__ float red[2][BN];                 // 1 KB  (total 66560 B -> 2 blocks/CU)

    const int tid  = threadIdx.x;
    const int lane = tid & 63;
    const int wv   = tid >> 6;
    const int wr   = wv >> 1;       // m half (0,1)
    const int wc   = wv & 1;        // n half (0,1)
    const int l31  = lane & 31;
    const int hi   = lane >> 5;     // 0,1

    // XCD-aware swizzle (4096 % 8 == 0): each XCD gets 32 consecutive m-tiles
    // x all 16 n-tiles -> A-tile re-reads are local-L2 hits.
    const int id = blockIdx.x;
    const int sw = (id & 7) * (4096 / 8) + (id >> 3);
    const int nt = sw & (NNT - 1);
    const int mt = sw >> 4;

    // Staging: 1024 16B-chunks per operand (128 rows x 8 chunks). LDS dest is
    // linear (wave-uniform base + lane*16); swizzle via inverse-permuted SOURCE
    // column c^(r&7) (involution with swz()).
    const unsigned short* aSrc[4];
    const unsigned short* bSrc[4];
    unsigned lOff[4];
#pragma unroll
    for (int i = 0; i < 4; ++i) {
        int idx = i * 256 + tid;
        int r = idx >> 3, c = idx & 7;
        aSrc[i] = Abf + (size_t)(mt * BM + r) * E_ + (c ^ (r & 7)) * 8;
        bSrc[i] = Bbf + (size_t)(nt * BN + r) * E_ + (c ^ (r & 7)) * 8;
        lOff[i] = (unsigned)(i * 256 + wv * 64) * 8;   // bf16-elem offset, wave-uniform
    }

    f32x16 acc[2][2];
#pragma unroll
    for (int i = 0; i < 2; ++i)
#pragma unroll
        for (int j = 0; j < 2; ++j)
#pragma unroll
            for (int r = 0; r < 16; ++r) acc[i][j][r] = 0.f;

#define ISSUE(tt, bb)                                                          \
    do {                                                                       \
        const size_t ko_ = (size_t)(tt) * BKS;                                 \
        _Pragma("unroll")                                                      \
        for (int i_ = 0; i_ < 4; ++i_) {                                       \
            GLDS16(aSrc[i_] + ko_, &As[bb][lOff[i_]]);                         \
            GLDS16(bSrc[i_] + ko_, &Bs[bb][lOff[i_]]);                         \
        }                                                                      \
    } while (0)

#define COMPUTE(bb)                                                            \
    do {                                                                       \
        const char* Ab_ = (const char*)As[bb];                                 \
        const char* Bb_ = (const char*)Bs[bb];                                 \
        _Pragma("unroll")                                                      \
        for (int kk = 0; kk < 4; ++kk) {                                       \
            const int kbyte = kk * 32 + hi * 16;                               \
            short8 af[2], bfr[2];                                              \
            _Pragma("unroll")                                                  \
            for (int mf = 0; mf < 2; ++mf)                                     \
                af[mf] = *(const short8*)(Ab_ + swz(wr * 64 + mf * 32 + l31, kbyte)); \
            _Pragma("unroll")                                                  \
            for (int nf = 0; nf < 2; ++nf)                                     \
                bfr[nf] = *(const short8*)(Bb_ + swz(wc * 64 + nf * 32 + l31, kbyte)); \
            _Pragma("unroll")                                                  \
            for (int mf = 0; mf < 2; ++mf)                                     \
                _Pragma("unroll")                                              \
                for (int nf = 0; nf < 2; ++nf)                                 \
                    acc[mf][nf] = __builtin_amdgcn_mfma_f32_32x32x16_bf16(     \
                        af[mf], bfr[nf], acc[mf][nf], 0, 0, 0);                \
        }                                                                      \
    } while (0)

    // prologue: stage 0 into buffer 0
    ISSUE(0, 0);
    __syncthreads();   // drains vmcnt(0): stage 0 resident

    int buf = 0;
    for (int t = 0; t < NSTAGE; ++t) {
        if (t + 1 < NSTAGE) ISSUE(t + 1, buf ^ 1);   // fly under MFMA
        COMPUTE(buf);
        __syncthreads();   // drains vmcnt (next stage resident) + fences reads
        buf ^= 1;
    }

    // Epilogue: d = sqrt(max(x2 + y2 - 2*xy, 0)); write dist (n<2000); fused min.
    // 32x32 C/D layout: col = lane&31, row = (reg&3) + 8*(reg>>2) + 4*(lane>>5).
    float y2v[2];
#pragma unroll
    for (int nf = 0; nf < 2; ++nf)
        y2v[nf] = y2g[nt * BN + wc * 64 + nf * 32 + l31];

    float mloc[2];
    mloc[0] = 3.4e38f; mloc[1] = 3.4e38f;

#pragma unroll
    for (int mf = 0; mf < 2; ++mf) {
        float x2v[16];
#pragma unroll
        for (int rg = 0; rg < 16; ++rg) {
            int row_l = (rg & 3) + 8 * (rg >> 2) + 4 * hi;
            x2v[rg] = x2g[mt * BM + wr * 64 + mf * 32 + row_l];
        }
#pragma unroll
        for (int nf = 0; nf < 2; ++nf) {
            int n = nt * BN + wc * 64 + nf * 32 + l31;
            int p = n / K_;
            int k = n - p * K_;
            bool valid = (n < NROWS_B);
#pragma unroll
            for (int rg = 0; rg < 16; ++rg) {
                int row_l = (rg & 3) + 8 * (rg >> 2) + 4 * hi;
                int m = mt * BM + wr * 64 + mf * 32 + row_l;
                int b = m >> 9;
                int s = m & (S_ - 1);
                float d2 = x2v[rg] + y2v[nf] - 2.f * acc[mf][nf][rg];
                float d  = sqrtf(fmaxf(d2, 0.f));
                if (valid) dist[(((size_t)b * P_ + p) * S_ + s) * K_ + k] = d;
                mloc[nf] = fminf(mloc[nf], d);
            }
        }
    }

    // combine hi halves: lanes l and l+32 share a col, cover complementary rows
#pragma unroll
    for (int nf = 0; nf < 2; ++nf)
        mloc[nf] = fminf(mloc[nf], __shfl_xor(mloc[nf], 32));
    if (hi == 0) {
#pragma unroll
        for (int nf = 0; nf < 2; ++nf)
            red[wr][wc * 64 + nf * 32 + l31] = mloc[nf];
    }
    __syncthreads();
    if (tid < BN) {
        float v = fminf(red[0][tid], red[1][tid]);
        ws_min[(size_t)mt * NB_PAD + nt * BN + tid] = v;
    }
#undef ISSUE
#undef COMPUTE
}

// ---------------------------------------------------------------------------
// Final: min over 4 m-subtiles, mean over k -> pd; then FC. One block per b.
__global__ __launch_bounds__(256) void mean_fc(const float* __restrict__ ws_min,
                                               const float* __restrict__ fcw,
                                               float* __restrict__ pd,
                                               float* __restrict__ cls) {
    const int b = blockIdx.x;
    const int t = threadIdx.x;
    __shared__ float pds[P_];
    if (t < P_) {
        float sum = 0.f;
#pragma unroll
        for (int k = 0; k < K_; ++k) {
            float m = 3.4e38f;
#pragma unroll
            for (int st = 0; st < 4; ++st)
                m = fminf(m, ws_min[(size_t)(b * 4 + st) * NB_PAD + t * K_ + k]);
            sum += m;
        }
        float v = sum * (1.0f / K_);
        pd[b * P_ + t] = v;
        pds[t] = v;
    }
    __syncthreads();
    if (t < C_) {
        float s = 0.f;
        for (int p = 0; p < P_; ++p) s += pds[p] * fcw[t * P_ + p];
        cls[b * C_ + t] = s;
    }
}

// ---------------------------------------------------------------------------
// Fallback path (no-workspace): round-3 fused kernel + min_mean + fc.
#define FBM 128
#define FBN 80
__device__ __forceinline__ int swzf(int row, int kbyte) {
    return (row * (BKS * 2) + kbyte) ^ ((row & 7) << 4);
}
__global__ __launch_bounds__(256) void dist_mfma_fb(const float* __restrict__ emb,
                                                    const float* __restrict__ proto,
                                                    float* __restrict__ dist) {
    __shared__ short As[FBM * BKS];
    __shared__ short Bs[FBN * BKS];
    __shared__ float x2s[FBM];
    __shared__ float y2s[FBN];

    const int tid  = threadIdx.x;
    const int lane = tid & 63;
    const int wv   = tid >> 6;
    const int l15  = lane & 15;
    const int lh   = lane >> 4;

    const int id = blockIdx.x;
    const int sw = (id & 7) * (6400 / 8) + (id >> 3);
    const int nt = sw % 25;
    const int mt = sw / 25;

    const float* Ab = emb + (size_t)mt * FBM * E_ + (size_t)(tid >> 4) * E_ + (tid & 15) * 4;
    const float* Bb = proto + (size_t)nt * FBN * E_ + (size_t)(tid >> 4) * E_ + (tid & 15) * 4;

    f32x4 acc[2][5];
#pragma unroll
    for (int i = 0; i < 2; ++i)
#pragma unroll
        for (int j = 0; j < 5; ++j) acc[i][j] = (f32x4){0.f, 0.f, 0.f, 0.f};

    float x2p[8], y2p[5];
#pragma unroll
    for (int i = 0; i < 8; ++i) x2p[i] = 0.f;
#pragma unroll
    for (int i = 0; i < 5; ++i) y2p[i] = 0.f;

    float4 pa[8], pb[5];
#pragma unroll
    for (int i = 0; i < 8; ++i) pa[i] = *(const float4*)(Ab + (size_t)i * 16 * E_);
#pragma unroll
    for (int i = 0; i < 5; ++i) pb[i] = *(const float4*)(Bb + (size_t)i * 16 * E_);

    for (int t = 0; t < NSTAGE; ++t) {
        ushort4 ca[8];
#pragma unroll
        for (int i = 0; i < 8; ++i) {
            float4 v = pa[i];
            x2p[i] += v.x * v.x + v.y * v.y + v.z * v.z + v.w * v.w;
            ca[i] = (ushort4){ f2bf(v.x), f2bf(v.y), f2bf(v.z), f2bf(v.w) };
        }
        ushort4 cb[5];
#pragma unroll
        for (int i = 0; i < 5; ++i) {
            float4 v = pb[i];
            y2p[i] += v.x * v.x + v.y * v.y + v.z * v.z + v.w * v.w;
            cb[i] = (ushort4){ f2bf(v.x), f2bf(v.y), f2bf(v.z), f2bf(v.w) };
        }
        __syncthreads();
#pragma unroll
        for (int i = 0; i < 8; ++i) {
            int idx = i * 256 + tid;
            *(ushort4*)((char*)As + swzf(idx >> 4, (idx & 15) * 8)) = ca[i];
        }
#pragma unroll
        for (int i = 0; i < 5; ++i) {
            int idx = i * 256 + tid;
            *(ushort4*)((char*)Bs + swzf(idx >> 4, (idx & 15) * 8)) = cb[i];
        }
        __syncthreads();
        if (t + 1 < NSTAGE) {
            const float* An = Ab + (size_t)(t + 1) * BKS;
            const float* Bn = Bb + (size_t)(t + 1) * BKS;
#pragma unroll
            for (int i = 0; i < 8; ++i) pa[i] = *(const float4*)(An + (size_t)i * 16 * E_);
#pragma unroll
            for (int i = 0; i < 5; ++i) pb[i] = *(const float4*)(Bn + (size_t)i * 16 * E_);
        }
#pragma unroll
        for (int kk = 0; kk < 2; ++kk) {
            const int kbyte = kk * 64 + lh * 16;
            short8 af[2];
#pragma unroll
            for (int mf = 0; mf < 2; ++mf)
                af[mf] = *(const short8*)((const char*)As + swzf(wv * 32 + mf * 16 + l15, kbyte));
            short8 bfr[5];
#pragma unroll
            for (int nf = 0; nf < 5; ++nf)
                bfr[nf] = *(const short8*)((const char*)Bs + swzf(nf * 16 + l15, kbyte));
#pragma unroll
            for (int mf = 0; mf < 2; ++mf)
#pragma unroll
                for (int nf = 0; nf < 5; ++nf)
                    acc[mf][nf] = __builtin_amdgcn_mfma_f32_16x16x32_bf16(
                        af[mf], bfr[nf], acc[mf][nf], 0, 0, 0);
        }
    }

#pragma unroll
    for (int i = 0; i < 8; ++i) {
        float v = x2p[i];
        v += __shfl_xor(v, 1); v += __shfl_xor(v, 2);
        v += __shfl_xor(v, 4); v += __shfl_xor(v, 8);
        if (l15 == 0) x2s[16 * i + (tid >> 4)] = v;
    }
#pragma unroll
    for (int i = 0; i < 5; ++i) {
        float v = y2p[i];
        v += __shfl_xor(v, 1); v += __shfl_xor(v, 2);
        v += __shfl_xor(v, 4); v += __shfl_xor(v, 8);
        if (l15 == 0) y2s[16 * i + (tid >> 4)] = v;
    }
    __syncthreads();

#pragma unroll
    for (int mf = 0; mf < 2; ++mf) {
#pragma unroll
        for (int nf = 0; nf < 5; ++nf) {
#pragma unroll
            for (int rg = 0; rg < 4; ++rg) {
                int ml = wv * 32 + mf * 16 + lh * 4 + rg;
                int nl = nf * 16 + l15;
                int m = mt * FBM + ml;
                int n = nt * FBN + nl;
                int b = m >> 9;
                int s = m & (S_ - 1);
                int p = n / K_;
                int k = n - p * K_;
                float d2 = x2s[ml] + y2s[nl] - 2.f * acc[mf][nf][rg];
                dist[(((size_t)b * P_ + p) * S_ + s) * K_ + k] = sqrtf(fmaxf(d2, 0.f));
            }
        }
    }
}

__global__ __launch_bounds__(256) void min_mean(const float* __restrict__ dist,
                                                float* __restrict__ pd) {
    const int p = blockIdx.x;
    const int b = blockIdx.y;
    const float* dp = dist + ((size_t)b * P_ + p) * (size_t)(S_ * K_);
    const int tid = threadIdx.x;

    const float4* base = (const float4*)(dp + (size_t)tid * 20);
    float4 q0 = base[0], q1 = base[1], q2 = base[2], q3 = base[3], q4 = base[4];

    float mn[K_];
    mn[0] = fminf(q0.x, q2.z); mn[1] = fminf(q0.y, q2.w);
    mn[2] = fminf(q0.z, q3.x); mn[3] = fminf(q0.w, q3.y);
    mn[4] = fminf(q1.x, q3.z); mn[5] = fminf(q1.y, q3.w);
    mn[6] = fminf(q1.z, q4.x); mn[7] = fminf(q1.w, q4.y);
    mn[8] = fminf(q2.x, q4.z); mn[9] = fminf(q2.y, q4.w);

#pragma unroll
    for (int k = 0; k < K_; ++k) {
#pragma unroll
        for (int off = 32; off > 0; off >>= 1)
            mn[k] = fminf(mn[k], __shfl_xor(mn[k], off));
    }

    __shared__ float red[4][K_];
    if ((tid & 63) == 0) {
#pragma unroll
        for (int k = 0; k < K_; ++k) red[tid >> 6][k] = mn[k];
    }
    __syncthreads();
    if (tid == 0) {
        float sum = 0.f;
#pragma unroll
        for (int k = 0; k < K_; ++k)
            sum += fminf(fminf(red[0][k], red[1][k]), fminf(red[2][k], red[3][k]));
        pd[b * P_ + p] = sum * (1.0f / K_);
    }
}

__global__ void fc_kernel(const float* __restrict__ pd, const float* __restrict__ fc,
                          float* __restrict__ cls) {
    int tid = threadIdx.x;
    if (tid < B_ * C_) {
        int b = tid / C_;
        int c = tid % C_;
        float s = 0.f;
        for (int p = 0; p < P_; ++p) s += pd[b * P_ + p] * fc[c * P_ + p];
        cls[b * C_ + c] = s;
    }
}

extern "C" void kernel_launch(void* const* d_in, const int* in_sizes, int n_in,
                              void* d_out, int out_size, void* d_ws, size_t ws_size,
                              hipStream_t stream) {
    const float* emb   = (const float*)d_in[0];   // [64,512,1024]
    const float* proto = (const float*)d_in[1];   // [200,10,1024]
    const float* fc    = (const float*)d_in[2];   // [3,200]
    float* out = (float*)d_out;

    float* pd   = out;                                                // [64,200]
    float* dist = out + (size_t)B_ * P_;                              // [64,200,512,10]
    float* cls  = out + (size_t)B_ * P_ + (size_t)B_ * P_ * S_ * K_;  // [64,3]

    const size_t bf_bytes  = (size_t)NROWS_P * E_ * 2;                // 71,303,168
    const size_t xy2_bytes = (size_t)NROWS_P * 4;                     // 139,264
    const size_t min_bytes = (size_t)NMT * NB_PAD * 4;                // 2,097,152
    const size_t ws_need   = bf_bytes + xy2_bytes + min_bytes;

    if (ws_size >= ws_need) {
        unsigned short* bf = (unsigned short*)d_ws;
        float* xy2    = (float*)((char*)d_ws + bf_bytes);
        float* ws_min = (float*)((char*)d_ws + bf_bytes + xy2_bytes);
        preconvert<<<NROWS_P / 4, 256, 0, stream>>>(emb, proto, bf, xy2);
        dist_gemm_bf<<<NMT * NNT, 256, 0, stream>>>(bf, bf + (size_t)NROWS_A * E_,
                                                    xy2, xy2 + NROWS_A, dist, ws_min);
        mean_fc<<<B_, 256, 0, stream>>>(ws_min, fc, pd, cls);
    } else {
        dist_mfma_fb<<<6400, 256, 0, stream>>>(emb, proto, dist);
        min_mean<<<dim3(P_, B_), 256, 0, stream>>>(dist, pd);
        fc_kernel<<<1, 256, 0, stream>>>(pd, fc, cls);
    }
}